// Round 7
// baseline (50.353 us; speedup 1.0000x reference)
//
#include <hip/hip_runtime.h>
#include <hip/hip_bf16.h>
#include <math.h>

#define N 8192
#define NRB 256            // split-K row blocks (2048 blocks total, 8/CU)
#define RPB (N / NRB)      // rows per block = 32

typedef float vfloat4 __attribute__((ext_vector_type(4)));

// Kernel 1: split-K partial vector-matrix product.
// y[j] = sum_i a[i] * w[i*N + j]
// grid (N/1024, NRB); block 256 threads x 4 cols (float4).
// a-chunk staged in LDS; launch_bounds(256,8) pins VGPR<=64 (8 blocks/CU,
// 32 waves/CU). Plain stores: the 8 MB partial buffer stays L2/MALL-hot
// for kernel 2 (nt variants measured slower in R6 — forced HBM round-trip).
__global__ __launch_bounds__(256, 8) void matvec_partial(
    const float* __restrict__ a, const float* __restrict__ w,
    float* __restrict__ partial)
{
    __shared__ float a_lds[RPB];

    const int col = blockIdx.x * 1024 + threadIdx.x * 4;
    const int rb  = blockIdx.y;
    const int r0  = rb * RPB;

    if (threadIdx.x < RPB) a_lds[threadIdx.x] = a[r0 + threadIdx.x];
    __syncthreads();

    const float* wp = w + (size_t)r0 * N + col;

    vfloat4 acc = (vfloat4)(0.f);
#pragma unroll 8
    for (int i = 0; i < RPB; ++i) {
        const float av = a_lds[i];              // ds_read, immediate offset
        const vfloat4 wv = *reinterpret_cast<const vfloat4*>(wp);
        acc += av * wv;
        wp += N;
    }
    *reinterpret_cast<vfloat4*>(partial + (size_t)rb * N + col) = acc;
}

// Kernel 2: fused partial-reduce + GLIF elementwise update.
// grid 256 blocks x 256 threads; block covers 32 columns (8 float4 groups).
// 32 row-subs each sum 8 of the 256 partial rows (cache-served float4
// loads); LDS tree; 32 threads finish the elementwise update.
__global__ __launch_bounds__(256) void glif_fused(
    const float* __restrict__ partial,
    const float* __restrict__ x_in,
    const float* __restrict__ v_in,
    const float* __restrict__ theta_s_in,
    const float* __restrict__ theta_v_in,
    const float* __restrict__ I_additive,
    const float* __restrict__ w,
    const float* __restrict__ E_L,
    const float* __restrict__ tau_m,
    const float* __restrict__ G,
    const float* __restrict__ R_I,
    const float* __restrict__ f_v,
    const float* __restrict__ f_I,
    const float* __restrict__ delta_theta_s,
    const float* __restrict__ b_s,
    const float* __restrict__ a_v,
    const float* __restrict__ b_v,
    const float* __restrict__ theta_inf,
    const float* __restrict__ delta_V,
    const float* __restrict__ I_A,
    float* __restrict__ out)
{
    __shared__ vfloat4 lds4[32][8];
    __shared__ float yrow[32];

    const int t  = threadIdx.x;
    const int g  = t & 7;           // float4 column group (cols j0+4g..+3)
    const int s  = t >> 3;          // row sub: rows s*8 .. s*8+7
    const int j0 = blockIdx.x * 32;

    const float* p = partial + (size_t)(s * 8) * N + j0 + g * 4;
    vfloat4 acc = (vfloat4)(0.f);
#pragma unroll
    for (int r = 0; r < 8; ++r) {
        acc += *reinterpret_cast<const vfloat4*>(p);
        p += N;
    }
    lds4[s][g] = acc;
    __syncthreads();

    if (t < 8) {
        vfloat4 y = lds4[0][t];
#pragma unroll
        for (int k = 1; k < 32; ++k) y += lds4[k][t];
        yrow[t * 4 + 0] = y.x;
        yrow[t * 4 + 1] = y.y;
        yrow[t * 4 + 2] = y.z;
        yrow[t * 4 + 3] = y.w;
    }
    __syncthreads();

    if (t < 32) {
        const int j = j0 + t;
        const float ssum = yrow[t];

        const float Iadd = I_additive[j];
        const float diag = w[(size_t)j * N + j];
        const float I = ssum - Iadd * diag + 0.85f * x_in[j];

        const float vj  = v_in[j];
        const float elj = E_L[j];
        const float ths = theta_s_in[j];
        const float thv = theta_v_in[j];

        const float dv     = (I * R_I[j] - G[j] * (vj - elj)) / tau_m[j];
        const float v_next = vj + dv;
        const float thresh = ths + thv;

        const float x = v_next - thresh;
        const float spiked_soft = 1.f / (1.f + expf(-x));

        const float spiked     = (v_next >= thresh) ? 1.f : 0.f;
        const float not_spiked = 1.f - spiked;

        const float v_reset = elj + f_v[j] * (vj - elj) - delta_V[j];
        const float v_new   = spiked * v_reset + not_spiked * v_next;

        const float theta_s_new = (1.f - b_s[j]) * ths + spiked * delta_theta_s[j];

        const float d_theta_v   = a_v[j] * (v_new - elj) - b_v[j] * (thv - theta_inf[j]);
        const float theta_v_new = thv + not_spiked * d_theta_v;

        const float I_additive_new = (1.f - f_I[j]) * Iadd + spiked_soft * I_A[j];

        out[j]         = spiked_soft;
        out[N + j]     = v_new;
        out[2 * N + j] = theta_s_new;
        out[3 * N + j] = theta_v_new;
        out[4 * N + j] = I_additive_new;
    }
}

// ---------- fallback path for tiny workspaces ----------
__global__ __launch_bounds__(256) void matvec_partial_var(
    const float* __restrict__ a, const float* __restrict__ w,
    float* __restrict__ partial, int rows_per_block)
{
    const int col = blockIdx.x * 1024 + threadIdx.x * 4;
    const int rb  = blockIdx.y;
    const float* wp = w + (size_t)rb * rows_per_block * N + col;
    const float* ap = a + rb * rows_per_block;
    vfloat4 acc = (vfloat4)(0.f);
#pragma unroll 4
    for (int i = 0; i < rows_per_block; ++i) {
        const float av = ap[i];
        const vfloat4 wv = *reinterpret_cast<const vfloat4*>(wp);
        acc += av * wv;
        wp += N;
    }
    *reinterpret_cast<vfloat4*>(partial + (size_t)rb * N + col) = acc;
}

__global__ __launch_bounds__(256) void glif_update_serial(
    const float* __restrict__ red, int cnt,
    const float* __restrict__ x_in,
    const float* __restrict__ v_in,
    const float* __restrict__ theta_s_in,
    const float* __restrict__ theta_v_in,
    const float* __restrict__ I_additive,
    const float* __restrict__ w,
    const float* __restrict__ E_L,
    const float* __restrict__ tau_m,
    const float* __restrict__ G,
    const float* __restrict__ R_I,
    const float* __restrict__ f_v,
    const float* __restrict__ f_I,
    const float* __restrict__ delta_theta_s,
    const float* __restrict__ b_s,
    const float* __restrict__ a_v,
    const float* __restrict__ b_v,
    const float* __restrict__ theta_inf,
    const float* __restrict__ delta_V,
    const float* __restrict__ I_A,
    float* __restrict__ out)
{
    const int j = blockIdx.x * blockDim.x + threadIdx.x;
    if (j >= N) return;
    float s = 0.f;
#pragma unroll 4
    for (int r = 0; r < cnt; ++r) s += red[(size_t)r * N + j];

    const float Iadd = I_additive[j];
    const float diag = w[(size_t)j * N + j];
    const float I = s - Iadd * diag + 0.85f * x_in[j];
    const float vj  = v_in[j];
    const float elj = E_L[j];
    const float ths = theta_s_in[j];
    const float thv = theta_v_in[j];
    const float dv     = (I * R_I[j] - G[j] * (vj - elj)) / tau_m[j];
    const float v_next = vj + dv;
    const float thresh = ths + thv;
    const float spiked_soft = 1.f / (1.f + expf(-(v_next - thresh)));
    const float spiked     = (v_next >= thresh) ? 1.f : 0.f;
    const float not_spiked = 1.f - spiked;
    const float v_reset = elj + f_v[j] * (vj - elj) - delta_V[j];
    const float v_new   = spiked * v_reset + not_spiked * v_next;
    const float theta_s_new = (1.f - b_s[j]) * ths + spiked * delta_theta_s[j];
    const float d_theta_v   = a_v[j] * (v_new - elj) - b_v[j] * (thv - theta_inf[j]);
    const float theta_v_new = thv + not_spiked * d_theta_v;
    const float I_additive_new = (1.f - f_I[j]) * Iadd + spiked_soft * I_A[j];
    out[j] = spiked_soft;
    out[N + j] = v_new;
    out[2 * N + j] = theta_s_new;
    out[3 * N + j] = theta_v_new;
    out[4 * N + j] = I_additive_new;
}

extern "C" void kernel_launch(void* const* d_in, const int* in_sizes, int n_in,
                              void* d_out, int out_size, void* d_ws, size_t ws_size,
                              hipStream_t stream) {
    const float* x_in          = (const float*)d_in[0];
    const float* v             = (const float*)d_in[1];
    const float* theta_s       = (const float*)d_in[2];
    const float* theta_v       = (const float*)d_in[3];
    const float* I_additive    = (const float*)d_in[4];
    const float* w             = (const float*)d_in[5];
    const float* E_L           = (const float*)d_in[6];
    const float* tau_m         = (const float*)d_in[7];
    const float* G             = (const float*)d_in[8];
    const float* R_I           = (const float*)d_in[9];
    const float* f_v           = (const float*)d_in[10];
    const float* f_I           = (const float*)d_in[11];
    const float* delta_theta_s = (const float*)d_in[12];
    const float* b_s           = (const float*)d_in[13];
    const float* a_v           = (const float*)d_in[14];
    const float* b_v           = (const float*)d_in[15];
    const float* theta_inf     = (const float*)d_in[16];
    const float* delta_V       = (const float*)d_in[17];
    const float* I_A           = (const float*)d_in[18];
    float* out     = (float*)d_out;
    float* partial = (float*)d_ws;

    if (ws_size >= (size_t)NRB * N * sizeof(float)) {
        dim3 grid1(N / 1024, NRB);
        matvec_partial<<<grid1, 256, 0, stream>>>(I_additive, w, partial);

        glif_fused<<<N / 32, 256, 0, stream>>>(
            partial, x_in, v, theta_s, theta_v, I_additive, w,
            E_L, tau_m, G, R_I, f_v, f_I, delta_theta_s, b_s, a_v, b_v,
            theta_inf, delta_V, I_A, out);
    } else {
        int nrb = 64;
        while (nrb > 1 && (size_t)nrb * N * sizeof(float) > ws_size) nrb >>= 1;
        dim3 grid1(N / 1024, nrb);
        matvec_partial_var<<<grid1, 256, 0, stream>>>(I_additive, w, partial, N / nrb);
        glif_update_serial<<<N / 256, 256, 0, stream>>>(
            partial, nrb, x_in, v, theta_s, theta_v, I_additive, w,
            E_L, tau_m, G, R_I, f_v, f_I, delta_theta_s, b_s, a_v, b_v,
            theta_inf, delta_V, I_A, out);
    }
}

// Round 8
// 48.790 us; speedup vs baseline: 1.0320x; 1.0320x over previous
//
#include <hip/hip_runtime.h>
#include <hip/hip_bf16.h>
#include <math.h>

#define N 8192
#define NRB 256            // split-K row blocks (2048 blocks total, 8/CU)
#define RPB (N / NRB)      // rows per block = 32

// native vector type: required by __builtin_nontemporal_{load,store}
typedef float vfloat4 __attribute__((ext_vector_type(4)));

// Kernel 1: split-K partial vector-matrix product.
// y[j] = sum_i a[i] * w[i*N + j]
// grid (N/1024, NRB); block 256 threads x 4 cols (float4).
// a-chunk staged in LDS (kills the per-iter 4B broadcast VMEM load);
// launch_bounds(256,8) pins VGPR<=64 so 8 blocks/CU (32 waves/CU).
// nt partial store: keep the streamed partial out of the w read path.
// [R5 config: best measured 48.99 us; R6 L3-partition and R7 plain-store
//  variants both regressed ~1 us.]
__global__ __launch_bounds__(256, 8) void matvec_partial(
    const float* __restrict__ a, const float* __restrict__ w,
    float* __restrict__ partial)
{
    __shared__ float a_lds[RPB];

    const int col = blockIdx.x * 1024 + threadIdx.x * 4;
    const int rb  = blockIdx.y;
    const int r0  = rb * RPB;

    if (threadIdx.x < RPB) a_lds[threadIdx.x] = a[r0 + threadIdx.x];
    __syncthreads();

    const float* wp = w + (size_t)r0 * N + col;

    vfloat4 acc = (vfloat4)(0.f);
#pragma unroll 8
    for (int i = 0; i < RPB; ++i) {
        const float av = a_lds[i];              // ds_read, immediate offset
        const vfloat4 wv = *reinterpret_cast<const vfloat4*>(wp);
        acc += av * wv;
        wp += N;
    }
    __builtin_nontemporal_store(acc,
        reinterpret_cast<vfloat4*>(partial + (size_t)rb * N + col));
}

// Kernel 2: fused partial-reduce + GLIF elementwise update.
// grid 128 blocks x 256 threads. Block covers 64 columns (16 float4 groups);
// 16 row-subs each sum 16 of the 256 partial rows with float4 nt loads;
// LDS tree; threads 0..63 finish the elementwise update.
__global__ __launch_bounds__(256) void glif_fused(
    const float* __restrict__ partial,
    const float* __restrict__ x_in,
    const float* __restrict__ v_in,
    const float* __restrict__ theta_s_in,
    const float* __restrict__ theta_v_in,
    const float* __restrict__ I_additive,
    const float* __restrict__ w,
    const float* __restrict__ E_L,
    const float* __restrict__ tau_m,
    const float* __restrict__ G,
    const float* __restrict__ R_I,
    const float* __restrict__ f_v,
    const float* __restrict__ f_I,
    const float* __restrict__ delta_theta_s,
    const float* __restrict__ b_s,
    const float* __restrict__ a_v,
    const float* __restrict__ b_v,
    const float* __restrict__ theta_inf,
    const float* __restrict__ delta_V,
    const float* __restrict__ I_A,
    float* __restrict__ out)
{
    __shared__ vfloat4 lds4[16][16];
    __shared__ float yrow[64];

    const int t  = threadIdx.x;
    const int g  = t & 15;          // float4 column group (cols j0+4g..+3)
    const int s  = t >> 4;          // row sub: rows s*16 .. s*16+15
    const int j0 = blockIdx.x * 64;

    const float* p = partial + (size_t)(s * 16) * N + j0 + g * 4;
    vfloat4 acc = (vfloat4)(0.f);
#pragma unroll
    for (int r = 0; r < 16; ++r) {
        acc += __builtin_nontemporal_load(reinterpret_cast<const vfloat4*>(p));
        p += N;
    }
    lds4[s][g] = acc;
    __syncthreads();

    if (t < 16) {
        vfloat4 y = lds4[0][t];
#pragma unroll
        for (int k = 1; k < 16; ++k) y += lds4[k][t];
        yrow[t * 4 + 0] = y.x;
        yrow[t * 4 + 1] = y.y;
        yrow[t * 4 + 2] = y.z;
        yrow[t * 4 + 3] = y.w;
    }
    __syncthreads();

    if (t < 64) {
        const int j = j0 + t;
        const float ssum = yrow[t];

        const float Iadd = I_additive[j];
        const float diag = w[(size_t)j * N + j];
        const float I = ssum - Iadd * diag + 0.85f * x_in[j];

        const float vj  = v_in[j];
        const float elj = E_L[j];
        const float ths = theta_s_in[j];
        const float thv = theta_v_in[j];

        const float dv     = (I * R_I[j] - G[j] * (vj - elj)) / tau_m[j];
        const float v_next = vj + dv;
        const float thresh = ths + thv;

        const float x = v_next - thresh;
        const float spiked_soft = 1.f / (1.f + expf(-x));

        const float spiked     = (v_next >= thresh) ? 1.f : 0.f;
        const float not_spiked = 1.f - spiked;

        const float v_reset = elj + f_v[j] * (vj - elj) - delta_V[j];
        const float v_new   = spiked * v_reset + not_spiked * v_next;

        const float theta_s_new = (1.f - b_s[j]) * ths + spiked * delta_theta_s[j];

        const float d_theta_v   = a_v[j] * (v_new - elj) - b_v[j] * (thv - theta_inf[j]);
        const float theta_v_new = thv + not_spiked * d_theta_v;

        const float I_additive_new = (1.f - f_I[j]) * Iadd + spiked_soft * I_A[j];

        out[j]         = spiked_soft;
        out[N + j]     = v_new;
        out[2 * N + j] = theta_s_new;
        out[3 * N + j] = theta_v_new;
        out[4 * N + j] = I_additive_new;
    }
}

// ---------- fallback path for tiny workspaces ----------
__global__ __launch_bounds__(256) void matvec_partial_var(
    const float* __restrict__ a, const float* __restrict__ w,
    float* __restrict__ partial, int rows_per_block)
{
    const int col = blockIdx.x * 1024 + threadIdx.x * 4;
    const int rb  = blockIdx.y;
    const float* wp = w + (size_t)rb * rows_per_block * N + col;
    const float* ap = a + rb * rows_per_block;
    vfloat4 acc = (vfloat4)(0.f);
#pragma unroll 4
    for (int i = 0; i < rows_per_block; ++i) {
        const float av = ap[i];
        const vfloat4 wv = *reinterpret_cast<const vfloat4*>(wp);
        acc += av * wv;
        wp += N;
    }
    *reinterpret_cast<vfloat4*>(partial + (size_t)rb * N + col) = acc;
}

__global__ __launch_bounds__(256) void glif_update_serial(
    const float* __restrict__ red, int cnt,
    const float* __restrict__ x_in,
    const float* __restrict__ v_in,
    const float* __restrict__ theta_s_in,
    const float* __restrict__ theta_v_in,
    const float* __restrict__ I_additive,
    const float* __restrict__ w,
    const float* __restrict__ E_L,
    const float* __restrict__ tau_m,
    const float* __restrict__ G,
    const float* __restrict__ R_I,
    const float* __restrict__ f_v,
    const float* __restrict__ f_I,
    const float* __restrict__ delta_theta_s,
    const float* __restrict__ b_s,
    const float* __restrict__ a_v,
    const float* __restrict__ b_v,
    const float* __restrict__ theta_inf,
    const float* __restrict__ delta_V,
    const float* __restrict__ I_A,
    float* __restrict__ out)
{
    const int j = blockIdx.x * blockDim.x + threadIdx.x;
    if (j >= N) return;
    float s = 0.f;
#pragma unroll 4
    for (int r = 0; r < cnt; ++r) s += red[(size_t)r * N + j];

    const float Iadd = I_additive[j];
    const float diag = w[(size_t)j * N + j];
    const float I = s - Iadd * diag + 0.85f * x_in[j];
    const float vj  = v_in[j];
    const float elj = E_L[j];
    const float ths = theta_s_in[j];
    const float thv = theta_v_in[j];
    const float dv     = (I * R_I[j] - G[j] * (vj - elj)) / tau_m[j];
    const float v_next = vj + dv;
    const float thresh = ths + thv;
    const float spiked_soft = 1.f / (1.f + expf(-(v_next - thresh)));
    const float spiked     = (v_next >= thresh) ? 1.f : 0.f;
    const float not_spiked = 1.f - spiked;
    const float v_reset = elj + f_v[j] * (vj - elj) - delta_V[j];
    const float v_new   = spiked * v_reset + not_spiked * v_next;
    const float theta_s_new = (1.f - b_s[j]) * ths + spiked * delta_theta_s[j];
    const float d_theta_v   = a_v[j] * (v_new - elj) - b_v[j] * (thv - theta_inf[j]);
    const float theta_v_new = thv + not_spiked * d_theta_v;
    const float I_additive_new = (1.f - f_I[j]) * Iadd + spiked_soft * I_A[j];
    out[j] = spiked_soft;
    out[N + j] = v_new;
    out[2 * N + j] = theta_s_new;
    out[3 * N + j] = theta_v_new;
    out[4 * N + j] = I_additive_new;
}

extern "C" void kernel_launch(void* const* d_in, const int* in_sizes, int n_in,
                              void* d_out, int out_size, void* d_ws, size_t ws_size,
                              hipStream_t stream) {
    const float* x_in          = (const float*)d_in[0];
    const float* v             = (const float*)d_in[1];
    const float* theta_s       = (const float*)d_in[2];
    const float* theta_v       = (const float*)d_in[3];
    const float* I_additive    = (const float*)d_in[4];
    const float* w             = (const float*)d_in[5];
    const float* E_L           = (const float*)d_in[6];
    const float* tau_m         = (const float*)d_in[7];
    const float* G             = (const float*)d_in[8];
    const float* R_I           = (const float*)d_in[9];
    const float* f_v           = (const float*)d_in[10];
    const float* f_I           = (const float*)d_in[11];
    const float* delta_theta_s = (const float*)d_in[12];
    const float* b_s           = (const float*)d_in[13];
    const float* a_v           = (const float*)d_in[14];
    const float* b_v           = (const float*)d_in[15];
    const float* theta_inf     = (const float*)d_in[16];
    const float* delta_V       = (const float*)d_in[17];
    const float* I_A           = (const float*)d_in[18];
    float* out     = (float*)d_out;
    float* partial = (float*)d_ws;

    if (ws_size >= (size_t)NRB * N * sizeof(float)) {
        dim3 grid1(N / 1024, NRB);
        matvec_partial<<<grid1, 256, 0, stream>>>(I_additive, w, partial);

        glif_fused<<<N / 64, 256, 0, stream>>>(
            partial, x_in, v, theta_s, theta_v, I_additive, w,
            E_L, tau_m, G, R_I, f_v, f_I, delta_theta_s, b_s, a_v, b_v,
            theta_inf, delta_V, I_A, out);
    } else {
        int nrb = 64;
        while (nrb > 1 && (size_t)nrb * N * sizeof(float) > ws_size) nrb >>= 1;
        dim3 grid1(N / 1024, nrb);
        matvec_partial_var<<<grid1, 256, 0, stream>>>(I_additive, w, partial, N / nrb);
        glif_update_serial<<<N / 256, 256, 0, stream>>>(
            partial, nrb, x_in, v, theta_s, theta_v, I_additive, w,
            E_L, tau_m, G, R_I, f_v, f_I, delta_theta_s, b_s, a_v, b_v,
            theta_inf, delta_V, I_A, out);
    }
}